// Round 5
// baseline (95.024 us; speedup 1.0000x reference)
//
#include <hip/hip_runtime.h>

// y[b,co,h,w] = sum_{ci,kk} x[b,ci,h,w+kk-1] * wt[co,ci,kk]; roll(+1,H) folded into
// the store: computed row h lands at hout=(h+1)%28.
// GEMM: C[32 x 32pad] = W[32 x 384] * im2col(x); K order k = kk*128 + ci.
// mfma_f32_32x32x16_bf16; A[m=lane&31][k=(lane>>5)*8+j]; C/D: col=lane&31,
// row=(reg&3)+8*(reg>>2)+4*(lane>>5).
// Single fused kernel: weights staged per-block into LDS fragment layout (wt is
// only 48 KB, L2-resident chip-wide), so no scratch kernel / graph dependency.

#define CIN   128
#define COUT  32
#define HH    28
#define WW    28
#define CIP   136   // ci padded 128->136 (272B stride): conflict-light b128 reads
#define WPD   34    // wp = w+1; only wp=0 and wp=29 need zeroing (wp>=30 feeds discarded cols)
#define HROWS 4
#define NTHR  256

typedef __attribute__((ext_vector_type(8))) short short8;
typedef __attribute__((ext_vector_type(8))) __bf16 bf16x8;
typedef __attribute__((ext_vector_type(16))) float f32x16;

__device__ inline unsigned short f2bf_sw(float f) {
    union { float f; unsigned u; } v; v.f = f;
    return (unsigned short)((v.u + 0x7FFFu + ((v.u >> 16) & 1u)) >> 16);  // RNE
}

__device__ inline unsigned int pack_bf2(float a, float b) {
#if __has_builtin(__builtin_amdgcn_cvt_pk_bf16_f32)
    typedef __attribute__((ext_vector_type(2))) __bf16 bf16x2;
    bf16x2 t = __builtin_amdgcn_cvt_pk_bf16_f32(a, b);
    return __builtin_bit_cast(unsigned int, t);
#else
    return (unsigned)f2bf_sw(a) | ((unsigned)f2bf_sw(b) << 16);
#endif
}

__device__ inline unsigned short f2bf1(float a) {
    return (unsigned short)(pack_bf2(a, a) & 0xFFFFu);   // single v_cvt_pk inst
}

// ---- block = 256 thr = 4 waves = 4 h-rows of one b; grid 7 x 128 = 896 ----
__global__ __launch_bounds__(NTHR, 2) void conv_fused(
    const float* __restrict__ x,
    const float* __restrict__ wt,
    float* __restrict__ out)
{
    __shared__ __align__(16) unsigned short wfl[24 * 64 * 8];      // 24,576 B (A-fragments)
    __shared__ __align__(16) unsigned short xt[HROWS][WPD][CIP];   // 36,992 B

    const int tid = threadIdx.x;
    const int hq  = blockIdx.x;           // 0..6
    const int b   = blockIdx.y;           // 0..127
    const int h0  = hq * HROWS;
    const float* xb = x + (size_t)b * CIN * HH * WW;

    // ---- weights -> LDS A-fragment layout: wfl[(s*64+lane)*8+j] ----
    // 12288 floats = 3072 float4; 12 per thread, coalesced; scatter bf16 into LDS.
#pragma unroll
    for (int it = 0; it < 12; ++it) {
        int p0 = (tid + it * NTHR) * 4;
        float4 v = *(const float4*)(wt + p0);
        float vv[4] = {v.x, v.y, v.z, v.w};
#pragma unroll
        for (int e = 0; e < 4; ++e) {
            int p  = p0 + e;                  // flat index into wt
            int kk = p % 3, c = p / 3;        // c = co*128 + ci
            int co = c >> 7, ci = c & 127;
            int k  = kk * 128 + ci;           // global K index
            int s  = k >> 4;
            int lane = ((k >> 3) & 1) * 32 + co;
            int j  = k & 7;
            wfl[(s * 64 + lane) * 8 + j] = f2bf1(vv[e]);
        }
    }

    // ---- zero consumed halo rows: wp=0 (kk=0 left) and wp=29 (kk=2 right) ----
    {
        unsigned int* xu = (unsigned int*)xt;
        const int ROWU = CIP / 2;             // 68 u32 per wp-row
        for (int i = tid; i < HROWS * 2 * ROWU; i += NTHR) {
            int row = i / ROWU;               // 0..7
            int hl  = row >> 1;
            int wp  = (row & 1) ? 29 : 0;
            xu[(hl * WPD + wp) * ROWU + (i % ROWU)] = 0u;
        }
    }

    // ---- stage x -> xt[hl][1+w][ci]: ci-pairs so LDS writes are packed u32 ----
    // pair index q over w4(7) x hl(4) x ci-pair(64) = 1792; 7 per thread.
#pragma unroll
    for (int p = 0; p < 7; ++p) {
        int q   = tid + p * NTHR;
        int w4  = q % 7;
        int r   = q / 7;                      // 0..255
        int hl  = r & 3;
        int ci0 = (r >> 2) * 2;               // even ci
        const float* base = xb + ((size_t)ci0 * HH + (h0 + hl)) * WW + w4 * 4;
        float4 v0 = *(const float4*)(base);
        float4 v1 = *(const float4*)(base + HH * WW);
        int wp = 1 + w4 * 4;
        *(unsigned int*)&xt[hl][wp + 0][ci0] = pack_bf2(v0.x, v1.x);
        *(unsigned int*)&xt[hl][wp + 1][ci0] = pack_bf2(v0.y, v1.y);
        *(unsigned int*)&xt[hl][wp + 2][ci0] = pack_bf2(v0.z, v1.z);
        *(unsigned int*)&xt[hl][wp + 3][ci0] = pack_bf2(v0.w, v1.w);
    }

    __syncthreads();

    const int lane = tid & 63;
    const int hl   = tid >> 6;                // wave id = local h row
    const int n    = lane & 31;               // output w (valid < 28)
    const int half = lane >> 5;
    f32x16 acc = {0,0,0,0,0,0,0,0,0,0,0,0,0,0,0,0};

    // K-loop: 24 MFMA steps; A and B fragments both b128 reads from LDS
#pragma unroll
    for (int kk = 0; kk < 3; ++kk) {
#pragma unroll
        for (int u = 0; u < 8; ++u) {
            short8 afr = *(const short8*)&wfl[((kk * 8 + u) * 64 + lane) * 8];
            short8 bfr = *(const short8*)&xt[hl][n + kk][u * 16 + half * 8];
            acc = __builtin_amdgcn_mfma_f32_32x32x16_bf16(
                __builtin_bit_cast(bf16x8, afr),
                __builtin_bit_cast(bf16x8, bfr), acc, 0, 0, 0);
        }
    }

    // epilogue: roll(+1); pad columns n>=28 dropped
    if (n < WW) {
        const int hout = (h0 + hl + 1) % HH;
#pragma unroll
        for (int r = 0; r < 16; ++r) {
            int co = (r & 3) + 8 * (r >> 2) + 4 * half;
            out[(((size_t)b * COUT + co) * HH + hout) * WW + n] = acc[r];
        }
    }
}

extern "C" void kernel_launch(void* const* d_in, const int* in_sizes, int n_in,
                              void* d_out, int out_size, void* d_ws, size_t ws_size,
                              hipStream_t stream) {
    const float* x  = (const float*)d_in[0];
    const float* wt = (const float*)d_in[1];
    float* out = (float*)d_out;
    dim3 grid(HH / HROWS, 128);               // 7 x 128 = 896 blocks
    conv_fused<<<grid, NTHR, 0, stream>>>(x, wt, out);
}

// Round 6
// 93.200 us; speedup vs baseline: 1.0196x; 1.0196x over previous
//
#include <hip/hip_runtime.h>

// y[b,co,h,w] = sum_{ci,kk} x[b,ci,h,w+kk-1] * wt[co,ci,kk]; roll(+1,H) folded into
// the store: computed row h lands at hout=(h+1)%28.
// GEMM: C[32 x 32pad] = W[32 x 384] * im2col(x); K order k = kk*128 + ci.
// mfma_f32_32x32x16_bf16; A[m=lane&31][k=(lane>>5)*8+j]; C/D: col=lane&31,
// row=(reg&3)+8*(reg>>2)+4*(lane>>5).
// R6: max memory-level parallelism — weights from global wf (L2-hot, no LDS
// scatter), all x-loads issued up front, A-fragments double-buffered across the
// K-loop, entire 1792-block grid co-resident (LDS 18.5 KB, VGPR<=128).

#define CIN   128
#define COUT  32
#define HH    28
#define WW    28
#define CIP   136   // ci padded 128->136 (272B stride): uniform-bank b128 reads
#define WPD   34    // wp = w+1; only wp=0 and wp=29 need zeroing
#define HROWS 2
#define NTHR  128

typedef __attribute__((ext_vector_type(8))) short short8;
typedef __attribute__((ext_vector_type(8))) __bf16 bf16x8;
typedef __attribute__((ext_vector_type(16))) float f32x16;

__device__ inline unsigned short f2bf(float f) {
    union { float f; unsigned u; } v; v.f = f;
    return (unsigned short)((v.u + 0x7FFFu + ((v.u >> 16) & 1u)) >> 16);  // RNE
}

__device__ inline unsigned int pack_bf2(float a, float b) {
#if __has_builtin(__builtin_amdgcn_cvt_pk_bf16_f32)
    typedef __attribute__((ext_vector_type(2))) __bf16 bf16x2;
    bf16x2 t = __builtin_amdgcn_cvt_pk_bf16_f32(a, b);
    return __builtin_bit_cast(unsigned int, t);
#else
    return (unsigned)f2bf(a) | ((unsigned)f2bf(b) << 16);
#endif
}

// ---- weights -> A-fragment layout wf[s][lane][j], s=0..23 (24 KB, L2-resident) ----
__global__ void build_wfrag(const float* __restrict__ wt, unsigned short* __restrict__ wf) {
    int t = blockIdx.x * 256 + threadIdx.x;            // 24*64*8 = 12288
    if (t >= 24 * 64 * 8) return;
    int j = t & 7, lane = (t >> 3) & 63, s = t >> 9;
    int co = lane & 31;
    int k  = s * 16 + (lane >> 5) * 8 + j;
    int kk = k >> 7, ci = k & 127;
    wf[t] = f2bf(wt[((size_t)co * CIN + ci) * 3 + kk]);
}

// ---- main: block = 128 thr = 2 waves = 2 h-rows of one b; grid 14 x 128 = 1792 ----
__global__ __launch_bounds__(NTHR, 4) void conv_mfma(
    const float* __restrict__ x,
    const unsigned short* __restrict__ wf,
    float* __restrict__ out)
{
    __shared__ __align__(16) unsigned short xt[HROWS][WPD][CIP];   // 18,496 B

    const int tid = threadIdx.x;
    const int hp  = blockIdx.x;           // 0..13
    const int b   = blockIdx.y;           // 0..127
    const int h0  = hp * HROWS;
    const float* xb = x + (size_t)b * CIN * HH * WW;

    // ---- phase 1: issue ALL 14 x float4 loads (independent, max MLP) ----
    float4 v0[7], v1[7];
    int w4a[7], ra[7];
#pragma unroll
    for (int p = 0; p < 7; ++p) {
        int q   = tid + p * NTHR;
        int w4  = q % 7;
        int r   = q / 7;                  // 0..127
        int hl  = r & 1;
        int ci0 = (r >> 1) * 2;
        const float* base = xb + ((size_t)ci0 * HH + (h0 + hl)) * WW + w4 * 4;
        v0[p] = *(const float4*)(base);
        v1[p] = *(const float4*)(base + HH * WW);
        w4a[p] = w4; ra[p] = r;
    }

    // ---- phase 2 (covers load latency): zero consumed halo rows wp=0, wp=29 ----
    {
        unsigned int* xu = (unsigned int*)xt;
        const int ROWU = CIP / 2;          // 68 u32 per wp-row
        for (int i = tid; i < HROWS * 2 * ROWU; i += NTHR) {
            int row = i / ROWU;            // 0..3
            int hl  = row & 1;
            int wp  = (row >> 1) ? 29 : 0;
            xu[(hl * WPD + wp) * ROWU + (i % ROWU)] = 0u;
        }
    }

    // ---- phase 3: convert + packed-u32 LDS writes (ci-pair adjacent) ----
#pragma unroll
    for (int p = 0; p < 7; ++p) {
        int hl  = ra[p] & 1;
        int ci0 = (ra[p] >> 1) * 2;
        int wp  = 1 + w4a[p] * 4;
        *(unsigned int*)&xt[hl][wp + 0][ci0] = pack_bf2(v0[p].x, v1[p].x);
        *(unsigned int*)&xt[hl][wp + 1][ci0] = pack_bf2(v0[p].y, v1[p].y);
        *(unsigned int*)&xt[hl][wp + 2][ci0] = pack_bf2(v0[p].z, v1[p].z);
        *(unsigned int*)&xt[hl][wp + 3][ci0] = pack_bf2(v0[p].w, v1[p].w);
    }

    // ---- A-fragments batch 0 in flight before the barrier ----
    const int lane = tid & 63;
    const int hl   = tid >> 6;
    short8 cur[8], nxt[8];
#pragma unroll
    for (int u = 0; u < 8; ++u)
        cur[u] = *(const short8*)(wf + (size_t)(u * 64 + lane) * 8);

    __syncthreads();

    const int n    = lane & 31;           // output w (valid < 28)
    const int half = lane >> 5;
    f32x16 acc = {0,0,0,0,0,0,0,0,0,0,0,0,0,0,0,0};

    // ---- K-loop: 3 taps x 8 steps; next A-batch always in flight ----
#pragma unroll
    for (int kk = 0; kk < 3; ++kk) {
        if (kk < 2) {
#pragma unroll
            for (int u = 0; u < 8; ++u)
                nxt[u] = *(const short8*)(wf + (size_t)(((kk + 1) * 8 + u) * 64 + lane) * 8);
        }
#pragma unroll
        for (int u = 0; u < 8; ++u) {
            short8 bfr = *(const short8*)&xt[hl][n + kk][u * 16 + half * 8];
            acc = __builtin_amdgcn_mfma_f32_32x32x16_bf16(
                __builtin_bit_cast(bf16x8, cur[u]),
                __builtin_bit_cast(bf16x8, bfr), acc, 0, 0, 0);
        }
#pragma unroll
        for (int u = 0; u < 8; ++u) cur[u] = nxt[u];   // reg rename, no copies after unroll
    }

    // ---- epilogue: roll(+1); pad columns n>=28 dropped ----
    if (n < WW) {
        const int hout = (h0 + hl + 1) % HH;
#pragma unroll
        for (int r = 0; r < 16; ++r) {
            int co = (r & 3) + 8 * (r >> 2) + 4 * half;
            out[(((size_t)b * COUT + co) * HH + hout) * WW + n] = acc[r];
        }
    }
}

extern "C" void kernel_launch(void* const* d_in, const int* in_sizes, int n_in,
                              void* d_out, int out_size, void* d_ws, size_t ws_size,
                              hipStream_t stream) {
    const float* x  = (const float*)d_in[0];
    const float* wt = (const float*)d_in[1];
    float* out = (float*)d_out;
    unsigned short* wf = (unsigned short*)d_ws;    // 24,576 B of scratch

    build_wfrag<<<48, 256, 0, stream>>>(wt, wf);
    dim3 grid(HH / HROWS, 128);                    // 14 x 128 = 1792 blocks, all co-resident
    conv_mfma<<<grid, NTHR, 0, stream>>>(x, wf, out);
}